// Round 2
// baseline (569.868 us; speedup 1.0000x reference)
//
#include <hip/hip_runtime.h>
#include <hip/hip_fp16.h>

// R2: fix builtin name (legacy K=16 f16 MFMA is ...16x16x16f16, no underscore).
// Pipeline: cast(fp32->fp16) -> CPB tables -> QKV GEMM -> windowed attention -> proj GEMM.

typedef _Float16 half8 __attribute__((ext_vector_type(8)));
typedef _Float16 half4v __attribute__((ext_vector_type(4)));
typedef float floatx4 __attribute__((ext_vector_type(4)));

#define BW 512
#define NTOK 144
#define CDIM 384
#define NH 12
#define HD 32
#define MROWS (BW * NTOK)      // 73728
#define QKVN (3 * CDIM)        // 1152

__device__ inline void llds16(const void* g, void* l) {
    __builtin_amdgcn_global_load_lds((const __attribute__((address_space(1))) void*)g,
                                     (__attribute__((address_space(3))) void*)l, 16, 0, 0);
}

// ---------------- cast fp32 -> fp16, 8 elems/thread ----------------
__global__ __launch_bounds__(256) void cast_f2h(const float* __restrict__ s,
                                                _Float16* __restrict__ d, int n8) {
    int i = blockIdx.x * 256 + threadIdx.x;
    if (i >= n8) return;
    const float4* s4 = (const float4*)s;
    float4 a = s4[2 * i], b = s4[2 * i + 1];
    half8 h;
    h[0] = (_Float16)a.x; h[1] = (_Float16)a.y; h[2] = (_Float16)a.z; h[3] = (_Float16)a.w;
    h[4] = (_Float16)b.x; h[5] = (_Float16)b.y; h[6] = (_Float16)b.z; h[7] = (_Float16)b.w;
    ((half8*)d)[i] = h;
}

// ---------------- CPB MLP: 529 rel positions -> 12 heads ----------------
__global__ void cpb_table(const float* __restrict__ w1, const float* __restrict__ b1,
                          const float* __restrict__ w2, float* __restrict__ tab) {
    int t = threadIdx.x;
    if (t >= 529) return;
    float u0 = (float)((t / 23) - 11) * (12.0f / 11.0f);
    float u1 = (float)((t % 23) - 11) * (12.0f / 11.0f);
    float x0 = copysignf(log2f(fabsf(u0) + 1.0f) * (1.0f / 3.0f), u0);
    float x1 = copysignf(log2f(fabsf(u1) + 1.0f) * (1.0f / 3.0f), u1);
    float acc[12] = {};
    for (int j = 0; j < 512; j++) {
        float hj = fmaf(x0, w1[2 * j], fmaf(x1, w1[2 * j + 1], b1[j]));
        hj = fmaxf(hj, 0.0f);
#pragma unroll
        for (int q = 0; q < 12; q++) acc[q] += hj * w2[q * 512 + j];
    }
    for (int q = 0; q < 12; q++) tab[t * 12 + q] = acc[q];
}

// ---------------- CM[m][h][i][j] = mask[m,i,j] + 16*sigmoid(bias[h,i,j]) ----------------
__global__ __launch_bounds__(256) void build_cm(const float* __restrict__ mask,
                                                const float* __restrict__ tab,
                                                float* __restrict__ CM) {
    int e = blockIdx.x * 256 + threadIdx.x;
    if (e >= 4 * NH * NTOK * NTOK) return;
    int j = e % NTOK; int r1 = e / NTOK;
    int i = r1 % NTOK; int r2 = r1 / NTOK;
    int h = r2 % NH;   int m = r2 / NH;
    int rt = ((i / 12) - (j / 12) + 11) * 23 + ((i % 12) - (j % 12) + 11);
    float bv = tab[rt * 12 + h];
    CM[e] = mask[m * (NTOK * NTOK) + i * NTOK + j] + 16.0f / (1.0f + __expf(-bv));
}

// ---------------- GEMM: C[m,n] = A[m,:]·B[n,:] + bias[n]; A (M,K), B (N,K) fp16 ----------------
template <typename OutT>
__global__ __launch_bounds__(256) void gemm_bt(const _Float16* __restrict__ A,
                                               const _Float16* __restrict__ B,
                                               const float* __restrict__ bias,
                                               OutT* __restrict__ C, int M, int N, int K) {
    __shared__ __align__(16) _Float16 As[128 * 32];
    __shared__ __align__(16) _Float16 Bs[128 * 32];
    const int t = threadIdx.x;
    const int wv = t >> 6, l = t & 63;
    const int wm = wv >> 1, wn = wv & 1;
    const int lr = l & 15, lk = l >> 4;
    const long m0 = (long)blockIdx.y * 128, n0 = (long)blockIdx.x * 128;

    const int srow = t >> 2, scol = (t & 3) * 8;
    const _Float16* ag = A + (m0 + srow) * (long)K + scol;
    const _Float16* bg = B + (n0 + srow) * (long)K + scol;
    _Float16* asd = As + t * 8;
    _Float16* bsd = Bs + t * 8;

    floatx4 acc[4][4] = {};

    for (int k0 = 0; k0 < K; k0 += 32) {
        llds16(ag, asd);
        llds16(ag + 64 * (long)K, asd + 2048);
        llds16(bg, bsd);
        llds16(bg + 64 * (long)K, bsd + 2048);
        ag += 32; bg += 32;
        __syncthreads();
        half8 af[4], bf[4];
#pragma unroll
        for (int fi = 0; fi < 4; fi++)
            af[fi] = *(const half8*)&As[(wm * 64 + fi * 16 + lr) * 32 + lk * 8];
#pragma unroll
        for (int fj = 0; fj < 4; fj++)
            bf[fj] = *(const half8*)&Bs[(wn * 64 + fj * 16 + lr) * 32 + lk * 8];
#pragma unroll
        for (int fi = 0; fi < 4; fi++)
#pragma unroll
            for (int fj = 0; fj < 4; fj++)
                acc[fi][fj] = __builtin_amdgcn_mfma_f32_16x16x32_f16(af[fi], bf[fj], acc[fi][fj], 0, 0, 0);
        __syncthreads();
    }

#pragma unroll
    for (int fi = 0; fi < 4; fi++) {
        const long row = m0 + wm * 64 + fi * 16 + lk * 4;
#pragma unroll
        for (int fj = 0; fj < 4; fj++) {
            const long col = n0 + wn * 64 + fj * 16 + lr;
            const float bv = bias[col];
#pragma unroll
            for (int r = 0; r < 4; r++) {
                float v = acc[fi][fj][r] + bv;
                C[(row + r) * (long)N + col] = (OutT)v;
            }
        }
    }
}

// ---------------- windowed attention: one block per (window, head), 9 waves ----------------
__global__ __launch_bounds__(576) void attn_win(const _Float16* __restrict__ qkv,
                                                const float* __restrict__ CM,
                                                const float* __restrict__ lscale,
                                                _Float16* __restrict__ O) {
    __shared__ __align__(16) _Float16 Kn[NTOK * HD];        // 9216 B
    __shared__ __align__(16) _Float16 Vt[HD * NTOK];        // 9216 B (transposed: [d][token])
    __shared__ __align__(16) _Float16 P[9 * 16 * NTOK];     // 41472 B (per-wave 16x144)

    const int bid = blockIdx.x;
    const int w = bid / NH, h = bid % NH;
    const int t = threadIdx.x;
    const int wv = t >> 6, l = t & 63;
    const int lr = l & 15, lk = l >> 4;

    const float sc = expf(fminf(lscale[h], 4.6051701859880914f));  // exp(min(ls, log(100)))

    // ---- stage K (normalized) and V (transposed) ----
    {
        const int row = t >> 2, part = t & 3;
        const size_t base = (size_t)(w * NTOK + row) * QKVN + h * HD + part * 8;
        half8 kv = *(const half8*)(qkv + base + CDIM);
        float ss = 0.f;
#pragma unroll
        for (int j = 0; j < 8; j++) { float f = (float)kv[j]; ss += f * f; }
        ss += __shfl_xor(ss, 1); ss += __shfl_xor(ss, 2);
        float inv = 1.0f / fmaxf(sqrtf(ss), 1e-12f);
        half8 kn;
#pragma unroll
        for (int j = 0; j < 8; j++) kn[j] = (_Float16)((float)kv[j] * inv);
        *(half8*)&Kn[row * HD + part * 8] = kn;

        half8 vv = *(const half8*)(qkv + base + 2 * CDIM);
#pragma unroll
        for (int j = 0; j < 8; j++) Vt[(part * 8 + j) * NTOK + row] = vv[j];
    }
    __syncthreads();

    // ---- Q fragment for this wave's 16 rows: load global, normalize, fold in scale ----
    half8 aq;
    {
        const size_t qb = (size_t)(w * NTOK + wv * 16 + lr) * QKVN + h * HD + lk * 8;
        half8 q = *(const half8*)(qkv + qb);
        float ss = 0.f;
#pragma unroll
        for (int j = 0; j < 8; j++) { float f = (float)q[j]; ss += f * f; }
        ss += __shfl_xor(ss, 16); ss += __shfl_xor(ss, 32);
        float inv = sc / fmaxf(sqrtf(ss), 1e-12f);
#pragma unroll
        for (int j = 0; j < 8; j++) aq[j] = (_Float16)((float)q[j] * inv);
    }

    // ---- S = Qn Kn^T (16 x 144 per wave), + CM, softmax ----
    floatx4 s[9];
#pragma unroll
    for (int cj = 0; cj < 9; cj++) {
        half8 bk = *(const half8*)&Kn[(cj * 16 + lr) * HD + lk * 8];
        floatx4 z = {};
        s[cj] = __builtin_amdgcn_mfma_f32_16x16x32_f16(aq, bk, z, 0, 0, 0);
    }
    const float* cmb = CM + (size_t)((w & 3) * NH + h) * (NTOK * NTOK)
                     + (wv * 16 + lk * 4) * NTOK + lr;
#pragma unroll
    for (int cj = 0; cj < 9; cj++)
#pragma unroll
        for (int r = 0; r < 4; r++) s[cj][r] += cmb[r * NTOK + cj * 16];

    float sm[4];
#pragma unroll
    for (int r = 0; r < 4; r++) {
        float m = s[0][r];
#pragma unroll
        for (int cj = 1; cj < 9; cj++) m = fmaxf(m, s[cj][r]);
        m = fmaxf(m, __shfl_xor(m, 1)); m = fmaxf(m, __shfl_xor(m, 2));
        m = fmaxf(m, __shfl_xor(m, 4)); m = fmaxf(m, __shfl_xor(m, 8));
        float sum = 0.f;
#pragma unroll
        for (int cj = 0; cj < 9; cj++) { s[cj][r] = __expf(s[cj][r] - m); sum += s[cj][r]; }
        sum += __shfl_xor(sum, 1); sum += __shfl_xor(sum, 2);
        sum += __shfl_xor(sum, 4); sum += __shfl_xor(sum, 8);
        sm[r] = sum;
    }

    // ---- P -> LDS (C-layout rows == lk*4+r), then PV via MFMA ----
    _Float16* Pw = P + wv * 16 * NTOK;
#pragma unroll
    for (int cj = 0; cj < 9; cj++)
#pragma unroll
        for (int r = 0; r < 4; r++)
            Pw[(lk * 4 + r) * NTOK + cj * 16 + lr] = (_Float16)s[cj][r];
    __syncthreads();  // cross-lane P RAW within wave + keep waves aligned

    floatx4 o0 = {}, o1 = {};
#pragma unroll
    for (int kb = 0; kb < 4; kb++) {
        half8 ap = *(const half8*)&Pw[lr * NTOK + kb * 32 + lk * 8];
        half8 b0 = *(const half8*)&Vt[lr * NTOK + kb * 32 + lk * 8];
        half8 b1 = *(const half8*)&Vt[(16 + lr) * NTOK + kb * 32 + lk * 8];
        o0 = __builtin_amdgcn_mfma_f32_16x16x32_f16(ap, b0, o0, 0, 0, 0);
        o1 = __builtin_amdgcn_mfma_f32_16x16x32_f16(ap, b1, o1, 0, 0, 0);
    }
    {   // K tail: tokens 128..143 via legacy 16x16x16 (builtin name has no underscore)
        half4v at  = *(const half4v*)&Pw[lr * NTOK + 128 + lk * 4];
        half4v bt0 = *(const half4v*)&Vt[lr * NTOK + 128 + lk * 4];
        half4v bt1 = *(const half4v*)&Vt[(16 + lr) * NTOK + 128 + lk * 4];
        o0 = __builtin_amdgcn_mfma_f32_16x16x16f16(at, bt0, o0, 0, 0, 0);
        o1 = __builtin_amdgcn_mfma_f32_16x16x16f16(at, bt1, o1, 0, 0, 0);
    }

    const size_t ob = (size_t)(w * NTOK + wv * 16 + lk * 4) * CDIM + h * HD;
#pragma unroll
    for (int r = 0; r < 4; r++) {
        float inv = 1.0f / sm[r];
        O[ob + r * CDIM + lr]      = (_Float16)(o0[r] * inv);
        O[ob + r * CDIM + 16 + lr] = (_Float16)(o1[r] * inv);
    }
}

extern "C" void kernel_launch(void* const* d_in, const int* in_sizes, int n_in,
                              void* d_out, int out_size, void* d_ws, size_t ws_size,
                              hipStream_t stream) {
    const float* x     = (const float*)d_in[0];
    const float* mask  = (const float*)d_in[1];
    const float* qkv_w = (const float*)d_in[2];
    const float* qkv_b = (const float*)d_in[3];
    const float* lsc   = (const float*)d_in[4];
    const float* cw1   = (const float*)d_in[5];
    const float* cb1   = (const float*)d_in[6];
    const float* cw2   = (const float*)d_in[7];
    const float* pw    = (const float*)d_in[8];
    const float* pb    = (const float*)d_in[9];
    (void)in_sizes; (void)n_in; (void)out_size; (void)ws_size;

    char* ws = (char*)d_ws;
    float*    tab  = (float*)(ws);                    //    25,392 B
    float*    CM   = (float*)(ws + 25600);            // 3,981,312 B
    _Float16* qw_h = (_Float16*)(ws + 4006912);       //   884,736 B
    _Float16* pw_h = (_Float16*)(ws + 4891648);       //   294,912 B
    _Float16* x_h  = (_Float16*)(ws + 5186560);       // 56,623,104 B (reused as o_h after QKV GEMM)
    _Float16* qkvh = (_Float16*)(ws + 61809664);      // 169,869,312 B ; total ~221 MB
    _Float16* o_h  = x_h;

    cast_f2h<<<(MROWS * CDIM / 8) / 256, 256, 0, stream>>>(x, x_h, MROWS * CDIM / 8);
    cast_f2h<<<(QKVN * CDIM / 8) / 256, 256, 0, stream>>>(qkv_w, qw_h, QKVN * CDIM / 8);
    cast_f2h<<<(CDIM * CDIM / 8) / 256, 256, 0, stream>>>(pw, pw_h, CDIM * CDIM / 8);
    cpb_table<<<1, 576, 0, stream>>>(cw1, cb1, cw2, tab);
    build_cm<<<(4 * NH * NTOK * NTOK + 255) / 256, 256, 0, stream>>>(mask, tab, CM);

    gemm_bt<_Float16><<<dim3(QKVN / 128, MROWS / 128), 256, 0, stream>>>(
        x_h, qw_h, qkv_b, qkvh, MROWS, QKVN, CDIM);

    attn_win<<<BW * NH, 576, 0, stream>>>(qkvh, CM, lsc, o_h);

    gemm_bt<float><<<dim3(CDIM / 128, MROWS / 128), 256, 0, stream>>>(
        o_h, pw_h, pb, (float*)d_out, MROWS, CDIM, CDIM);
}

// Round 3
// 547.955 us; speedup vs baseline: 1.0400x; 1.0400x over previous
//
#include <hip/hip_runtime.h>
#include <hip/hip_fp16.h>

// R3: XCD-aware tile swizzle on both GEMMs (A-tile L2 reuse within an XCD),
// drop redundant barrier in attn_win, merge weight-cast launches.

typedef _Float16 half8 __attribute__((ext_vector_type(8)));
typedef _Float16 half4v __attribute__((ext_vector_type(4)));
typedef float floatx4 __attribute__((ext_vector_type(4)));

#define BW 512
#define NTOK 144
#define CDIM 384
#define NH 12
#define HD 32
#define MROWS (BW * NTOK)      // 73728
#define QKVN (3 * CDIM)        // 1152

__device__ inline void llds16(const void* g, void* l) {
    __builtin_amdgcn_global_load_lds((const __attribute__((address_space(1))) void*)g,
                                     (__attribute__((address_space(3))) void*)l, 16, 0, 0);
}

// ---------------- cast fp32 -> fp16, 8 elems/thread ----------------
__global__ __launch_bounds__(256) void cast_f2h(const float* __restrict__ s,
                                                _Float16* __restrict__ d, int n8) {
    int i = blockIdx.x * 256 + threadIdx.x;
    if (i >= n8) return;
    const float4* s4 = (const float4*)s;
    float4 a = s4[2 * i], b = s4[2 * i + 1];
    half8 h;
    h[0] = (_Float16)a.x; h[1] = (_Float16)a.y; h[2] = (_Float16)a.z; h[3] = (_Float16)a.w;
    h[4] = (_Float16)b.x; h[5] = (_Float16)b.y; h[6] = (_Float16)b.z; h[7] = (_Float16)b.w;
    ((half8*)d)[i] = h;
}

// cast both weight matrices in one launch
__global__ __launch_bounds__(256) void cast_weights(const float* __restrict__ w_qkv,
                                                    _Float16* __restrict__ qh,
                                                    const float* __restrict__ w_proj,
                                                    _Float16* __restrict__ ph) {
    const int nq = QKVN * CDIM / 8;            // 55296
    const int np = CDIM * CDIM / 8;            // 18432
    int i = blockIdx.x * 256 + threadIdx.x;
    const float4* s4; half8* d8; int j;
    if (i < nq) { s4 = (const float4*)w_qkv; d8 = (half8*)qh; j = i; }
    else if (i < nq + np) { s4 = (const float4*)w_proj; d8 = (half8*)ph; j = i - nq; }
    else return;
    float4 a = s4[2 * j], b = s4[2 * j + 1];
    half8 h;
    h[0] = (_Float16)a.x; h[1] = (_Float16)a.y; h[2] = (_Float16)a.z; h[3] = (_Float16)a.w;
    h[4] = (_Float16)b.x; h[5] = (_Float16)b.y; h[6] = (_Float16)b.z; h[7] = (_Float16)b.w;
    d8[j] = h;
}

// ---------------- CPB MLP: 529 rel positions -> 12 heads ----------------
__global__ void cpb_table(const float* __restrict__ w1, const float* __restrict__ b1,
                          const float* __restrict__ w2, float* __restrict__ tab) {
    int t = threadIdx.x;
    if (t >= 529) return;
    float u0 = (float)((t / 23) - 11) * (12.0f / 11.0f);
    float u1 = (float)((t % 23) - 11) * (12.0f / 11.0f);
    float x0 = copysignf(log2f(fabsf(u0) + 1.0f) * (1.0f / 3.0f), u0);
    float x1 = copysignf(log2f(fabsf(u1) + 1.0f) * (1.0f / 3.0f), u1);
    float acc[12] = {};
    for (int j = 0; j < 512; j++) {
        float hj = fmaf(x0, w1[2 * j], fmaf(x1, w1[2 * j + 1], b1[j]));
        hj = fmaxf(hj, 0.0f);
#pragma unroll
        for (int q = 0; q < 12; q++) acc[q] += hj * w2[q * 512 + j];
    }
    for (int q = 0; q < 12; q++) tab[t * 12 + q] = acc[q];
}

// ---------------- CM[m][h][i][j] = mask[m,i,j] + 16*sigmoid(bias[h,i,j]) ----------------
__global__ __launch_bounds__(256) void build_cm(const float* __restrict__ mask,
                                                const float* __restrict__ tab,
                                                float* __restrict__ CM) {
    int e = blockIdx.x * 256 + threadIdx.x;
    if (e >= 4 * NH * NTOK * NTOK) return;
    int j = e % NTOK; int r1 = e / NTOK;
    int i = r1 % NTOK; int r2 = r1 / NTOK;
    int h = r2 % NH;   int m = r2 / NH;
    int rt = ((i / 12) - (j / 12) + 11) * 23 + ((i % 12) - (j % 12) + 11);
    float bv = tab[rt * 12 + h];
    CM[e] = mask[m * (NTOK * NTOK) + i * NTOK + j] + 16.0f / (1.0f + __expf(-bv));
}

// ---------------- GEMM: C[m,n] = A[m,:]·B[n,:] + bias[n]; A (M,K), B (N,K) fp16 ----------------
// 1D grid, XCD-swizzled: each XCD owns a contiguous run of tiles, N-fastest,
// so tiles sharing an A row-block hit the same XCD's L2.
template <typename OutT>
__global__ __launch_bounds__(256) void gemm_bt(const _Float16* __restrict__ A,
                                               const _Float16* __restrict__ B,
                                               const float* __restrict__ bias,
                                               OutT* __restrict__ C, int M, int N, int K) {
    __shared__ __align__(16) _Float16 As[128 * 32];
    __shared__ __align__(16) _Float16 Bs[128 * 32];
    const int t = threadIdx.x;
    const int wv = t >> 6, l = t & 63;
    const int wm = wv >> 1, wn = wv & 1;
    const int lr = l & 15, lk = l >> 4;

    const int ntn = N >> 7;                       // N-tiles
    const int t8 = gridDim.x >> 3;                // tiles per XCD
    const int tile = (blockIdx.x & 7) * t8 + (blockIdx.x >> 3);
    const long m0 = (long)(tile / ntn) * 128, n0 = (long)(tile % ntn) * 128;

    const int srow = t >> 2, scol = (t & 3) * 8;
    const _Float16* ag = A + (m0 + srow) * (long)K + scol;
    const _Float16* bg = B + (n0 + srow) * (long)K + scol;
    _Float16* asd = As + t * 8;
    _Float16* bsd = Bs + t * 8;

    floatx4 acc[4][4] = {};

    for (int k0 = 0; k0 < K; k0 += 32) {
        llds16(ag, asd);
        llds16(ag + 64 * (long)K, asd + 2048);
        llds16(bg, bsd);
        llds16(bg + 64 * (long)K, bsd + 2048);
        ag += 32; bg += 32;
        __syncthreads();
        half8 af[4], bf[4];
#pragma unroll
        for (int fi = 0; fi < 4; fi++)
            af[fi] = *(const half8*)&As[(wm * 64 + fi * 16 + lr) * 32 + lk * 8];
#pragma unroll
        for (int fj = 0; fj < 4; fj++)
            bf[fj] = *(const half8*)&Bs[(wn * 64 + fj * 16 + lr) * 32 + lk * 8];
#pragma unroll
        for (int fi = 0; fi < 4; fi++)
#pragma unroll
            for (int fj = 0; fj < 4; fj++)
                acc[fi][fj] = __builtin_amdgcn_mfma_f32_16x16x32_f16(af[fi], bf[fj], acc[fi][fj], 0, 0, 0);
        __syncthreads();
    }

#pragma unroll
    for (int fi = 0; fi < 4; fi++) {
        const long row = m0 + wm * 64 + fi * 16 + lk * 4;
#pragma unroll
        for (int fj = 0; fj < 4; fj++) {
            const long col = n0 + wn * 64 + fj * 16 + lr;
            const float bv = bias[col];
#pragma unroll
            for (int r = 0; r < 4; r++) {
                float v = acc[fi][fj][r] + bv;
                C[(row + r) * (long)N + col] = (OutT)v;
            }
        }
    }
}

// ---------------- windowed attention: one block per (window, head), 9 waves ----------------
__global__ __launch_bounds__(576) void attn_win(const _Float16* __restrict__ qkv,
                                                const float* __restrict__ CM,
                                                const float* __restrict__ lscale,
                                                _Float16* __restrict__ O) {
    __shared__ __align__(16) _Float16 Kn[NTOK * HD];        // 9216 B
    __shared__ __align__(16) _Float16 Vt[HD * NTOK];        // 9216 B (transposed: [d][token])
    __shared__ __align__(16) _Float16 P[9 * 16 * NTOK];     // 41472 B (per-wave 16x144)

    const int bid = blockIdx.x;
    const int w = bid / NH, h = bid % NH;
    const int t = threadIdx.x;
    const int wv = t >> 6, l = t & 63;
    const int lr = l & 15, lk = l >> 4;

    const float sc = expf(fminf(lscale[h], 4.6051701859880914f));  // exp(min(ls, log(100)))

    // ---- stage K (normalized) and V (transposed) ----
    {
        const int row = t >> 2, part = t & 3;
        const size_t base = (size_t)(w * NTOK + row) * QKVN + h * HD + part * 8;
        half8 kv = *(const half8*)(qkv + base + CDIM);
        float ss = 0.f;
#pragma unroll
        for (int j = 0; j < 8; j++) { float f = (float)kv[j]; ss += f * f; }
        ss += __shfl_xor(ss, 1); ss += __shfl_xor(ss, 2);
        float inv = 1.0f / fmaxf(sqrtf(ss), 1e-12f);
        half8 kn;
#pragma unroll
        for (int j = 0; j < 8; j++) kn[j] = (_Float16)((float)kv[j] * inv);
        *(half8*)&Kn[row * HD + part * 8] = kn;

        half8 vv = *(const half8*)(qkv + base + 2 * CDIM);
#pragma unroll
        for (int j = 0; j < 8; j++) Vt[(part * 8 + j) * NTOK + row] = vv[j];
    }
    __syncthreads();

    // ---- Q fragment for this wave's 16 rows: load global, normalize, fold in scale ----
    half8 aq;
    {
        const size_t qb = (size_t)(w * NTOK + wv * 16 + lr) * QKVN + h * HD + lk * 8;
        half8 q = *(const half8*)(qkv + qb);
        float ss = 0.f;
#pragma unroll
        for (int j = 0; j < 8; j++) { float f = (float)q[j]; ss += f * f; }
        ss += __shfl_xor(ss, 16); ss += __shfl_xor(ss, 32);
        float inv = sc / fmaxf(sqrtf(ss), 1e-12f);
#pragma unroll
        for (int j = 0; j < 8; j++) aq[j] = (_Float16)((float)q[j] * inv);
    }

    // ---- S = Qn Kn^T (16 x 144 per wave), + CM, softmax ----
    floatx4 s[9];
#pragma unroll
    for (int cj = 0; cj < 9; cj++) {
        half8 bk = *(const half8*)&Kn[(cj * 16 + lr) * HD + lk * 8];
        floatx4 z = {};
        s[cj] = __builtin_amdgcn_mfma_f32_16x16x32_f16(aq, bk, z, 0, 0, 0);
    }
    const float* cmb = CM + (size_t)((w & 3) * NH + h) * (NTOK * NTOK)
                     + (wv * 16 + lk * 4) * NTOK + lr;
#pragma unroll
    for (int cj = 0; cj < 9; cj++)
#pragma unroll
        for (int r = 0; r < 4; r++) s[cj][r] += cmb[r * NTOK + cj * 16];

    float sm[4];
#pragma unroll
    for (int r = 0; r < 4; r++) {
        float m = s[0][r];
#pragma unroll
        for (int cj = 1; cj < 9; cj++) m = fmaxf(m, s[cj][r]);
        m = fmaxf(m, __shfl_xor(m, 1)); m = fmaxf(m, __shfl_xor(m, 2));
        m = fmaxf(m, __shfl_xor(m, 4)); m = fmaxf(m, __shfl_xor(m, 8));
        float sum = 0.f;
#pragma unroll
        for (int cj = 0; cj < 9; cj++) { s[cj][r] = __expf(s[cj][r] - m); sum += s[cj][r]; }
        sum += __shfl_xor(sum, 1); sum += __shfl_xor(sum, 2);
        sum += __shfl_xor(sum, 4); sum += __shfl_xor(sum, 8);
        sm[r] = sum;
    }

    // ---- P -> LDS (C-layout rows == lk*4+r), then PV via MFMA ----
    // P is written and read by the SAME wave; DS ops are wave-ordered, so no
    // block barrier is needed here (waves touch disjoint P slices; Kn/Vt are
    // read-only past the first barrier).
    _Float16* Pw = P + wv * 16 * NTOK;
#pragma unroll
    for (int cj = 0; cj < 9; cj++)
#pragma unroll
        for (int r = 0; r < 4; r++)
            Pw[(lk * 4 + r) * NTOK + cj * 16 + lr] = (_Float16)s[cj][r];

    floatx4 o0 = {}, o1 = {};
#pragma unroll
    for (int kb = 0; kb < 4; kb++) {
        half8 ap = *(const half8*)&Pw[lr * NTOK + kb * 32 + lk * 8];
        half8 b0 = *(const half8*)&Vt[lr * NTOK + kb * 32 + lk * 8];
        half8 b1 = *(const half8*)&Vt[(16 + lr) * NTOK + kb * 32 + lk * 8];
        o0 = __builtin_amdgcn_mfma_f32_16x16x32_f16(ap, b0, o0, 0, 0, 0);
        o1 = __builtin_amdgcn_mfma_f32_16x16x32_f16(ap, b1, o1, 0, 0, 0);
    }
    {   // K tail: tokens 128..143 via legacy 16x16x16 MFMA
        half4v at  = *(const half4v*)&Pw[lr * NTOK + 128 + lk * 4];
        half4v bt0 = *(const half4v*)&Vt[lr * NTOK + 128 + lk * 4];
        half4v bt1 = *(const half4v*)&Vt[(16 + lr) * NTOK + 128 + lk * 4];
        o0 = __builtin_amdgcn_mfma_f32_16x16x16f16(at, bt0, o0, 0, 0, 0);
        o1 = __builtin_amdgcn_mfma_f32_16x16x16f16(at, bt1, o1, 0, 0, 0);
    }

    const size_t ob = (size_t)(w * NTOK + wv * 16 + lk * 4) * CDIM + h * HD;
#pragma unroll
    for (int r = 0; r < 4; r++) {
        float inv = 1.0f / sm[r];
        O[ob + r * CDIM + lr]      = (_Float16)(o0[r] * inv);
        O[ob + r * CDIM + 16 + lr] = (_Float16)(o1[r] * inv);
    }
}

extern "C" void kernel_launch(void* const* d_in, const int* in_sizes, int n_in,
                              void* d_out, int out_size, void* d_ws, size_t ws_size,
                              hipStream_t stream) {
    const float* x     = (const float*)d_in[0];
    const float* mask  = (const float*)d_in[1];
    const float* qkv_w = (const float*)d_in[2];
    const float* qkv_b = (const float*)d_in[3];
    const float* lsc   = (const float*)d_in[4];
    const float* cw1   = (const float*)d_in[5];
    const float* cb1   = (const float*)d_in[6];
    const float* cw2   = (const float*)d_in[7];
    const float* pw    = (const float*)d_in[8];
    const float* pb    = (const float*)d_in[9];
    (void)in_sizes; (void)n_in; (void)out_size; (void)ws_size;

    char* ws = (char*)d_ws;
    float*    tab  = (float*)(ws);                    //    25,392 B
    float*    CM   = (float*)(ws + 25600);            // 3,981,312 B
    _Float16* qw_h = (_Float16*)(ws + 4006912);       //   884,736 B
    _Float16* pw_h = (_Float16*)(ws + 4891648);       //   294,912 B
    _Float16* x_h  = (_Float16*)(ws + 5186560);       // 56,623,104 B (reused as o_h after QKV GEMM)
    _Float16* qkvh = (_Float16*)(ws + 61809664);      // 169,869,312 B ; total ~221 MB
    _Float16* o_h  = x_h;

    cast_f2h<<<(MROWS * CDIM / 8) / 256, 256, 0, stream>>>(x, x_h, MROWS * CDIM / 8);
    cast_weights<<<(QKVN * CDIM / 8 + CDIM * CDIM / 8 + 255) / 256, 256, 0, stream>>>(
        qkv_w, qw_h, pw, pw_h);
    cpb_table<<<1, 576, 0, stream>>>(cw1, cb1, cw2, tab);
    build_cm<<<(4 * NH * NTOK * NTOK + 255) / 256, 256, 0, stream>>>(mask, tab, CM);

    gemm_bt<_Float16><<<(QKVN / 128) * (MROWS / 128), 256, 0, stream>>>(
        x_h, qw_h, qkv_b, qkvh, MROWS, QKVN, CDIM);

    attn_win<<<BW * NH, 576, 0, stream>>>(qkvh, CM, lsc, o_h);

    gemm_bt<float><<<(CDIM / 128) * (MROWS / 128), 256, 0, stream>>>(
        o_h, pw_h, pb, (float*)d_out, MROWS, CDIM, CDIM);
}

// Round 4
// 528.971 us; speedup vs baseline: 1.0773x; 1.0359x over previous
//
#include <hip/hip_runtime.h>
#include <hip/hip_fp16.h>

// R4: GEMM retile 128x128 -> 256x128 (512 thr / 8 waves, m97-shape 64x64 per wave).
// Halves barriers per FLOP, doubles resident waves. attn unchanged.

typedef _Float16 half8 __attribute__((ext_vector_type(8)));
typedef _Float16 half4v __attribute__((ext_vector_type(4)));
typedef float floatx4 __attribute__((ext_vector_type(4)));

#define BW 512
#define NTOK 144
#define CDIM 384
#define NH 12
#define HD 32
#define MROWS (BW * NTOK)      // 73728
#define QKVN (3 * CDIM)        // 1152

__device__ inline void llds16(const void* g, void* l) {
    __builtin_amdgcn_global_load_lds((const __attribute__((address_space(1))) void*)g,
                                     (__attribute__((address_space(3))) void*)l, 16, 0, 0);
}

// ---------------- cast fp32 -> fp16, 8 elems/thread ----------------
__global__ __launch_bounds__(256) void cast_f2h(const float* __restrict__ s,
                                                _Float16* __restrict__ d, int n8) {
    int i = blockIdx.x * 256 + threadIdx.x;
    if (i >= n8) return;
    const float4* s4 = (const float4*)s;
    float4 a = s4[2 * i], b = s4[2 * i + 1];
    half8 h;
    h[0] = (_Float16)a.x; h[1] = (_Float16)a.y; h[2] = (_Float16)a.z; h[3] = (_Float16)a.w;
    h[4] = (_Float16)b.x; h[5] = (_Float16)b.y; h[6] = (_Float16)b.z; h[7] = (_Float16)b.w;
    ((half8*)d)[i] = h;
}

// cast both weight matrices in one launch
__global__ __launch_bounds__(256) void cast_weights(const float* __restrict__ w_qkv,
                                                    _Float16* __restrict__ qh,
                                                    const float* __restrict__ w_proj,
                                                    _Float16* __restrict__ ph) {
    const int nq = QKVN * CDIM / 8;            // 55296
    const int np = CDIM * CDIM / 8;            // 18432
    int i = blockIdx.x * 256 + threadIdx.x;
    const float4* s4; half8* d8; int j;
    if (i < nq) { s4 = (const float4*)w_qkv; d8 = (half8*)qh; j = i; }
    else if (i < nq + np) { s4 = (const float4*)w_proj; d8 = (half8*)ph; j = i - nq; }
    else return;
    float4 a = s4[2 * j], b = s4[2 * j + 1];
    half8 h;
    h[0] = (_Float16)a.x; h[1] = (_Float16)a.y; h[2] = (_Float16)a.z; h[3] = (_Float16)a.w;
    h[4] = (_Float16)b.x; h[5] = (_Float16)b.y; h[6] = (_Float16)b.z; h[7] = (_Float16)b.w;
    d8[j] = h;
}

// ---------------- CPB MLP: 529 rel positions -> 12 heads ----------------
__global__ void cpb_table(const float* __restrict__ w1, const float* __restrict__ b1,
                          const float* __restrict__ w2, float* __restrict__ tab) {
    int t = threadIdx.x;
    if (t >= 529) return;
    float u0 = (float)((t / 23) - 11) * (12.0f / 11.0f);
    float u1 = (float)((t % 23) - 11) * (12.0f / 11.0f);
    float x0 = copysignf(log2f(fabsf(u0) + 1.0f) * (1.0f / 3.0f), u0);
    float x1 = copysignf(log2f(fabsf(u1) + 1.0f) * (1.0f / 3.0f), u1);
    float acc[12] = {};
    for (int j = 0; j < 512; j++) {
        float hj = fmaf(x0, w1[2 * j], fmaf(x1, w1[2 * j + 1], b1[j]));
        hj = fmaxf(hj, 0.0f);
#pragma unroll
        for (int q = 0; q < 12; q++) acc[q] += hj * w2[q * 512 + j];
    }
    for (int q = 0; q < 12; q++) tab[t * 12 + q] = acc[q];
}

// ---------------- CM[m][h][i][j] = mask[m,i,j] + 16*sigmoid(bias[h,i,j]) ----------------
__global__ __launch_bounds__(256) void build_cm(const float* __restrict__ mask,
                                                const float* __restrict__ tab,
                                                float* __restrict__ CM) {
    int e = blockIdx.x * 256 + threadIdx.x;
    if (e >= 4 * NH * NTOK * NTOK) return;
    int j = e % NTOK; int r1 = e / NTOK;
    int i = r1 % NTOK; int r2 = r1 / NTOK;
    int h = r2 % NH;   int m = r2 / NH;
    int rt = ((i / 12) - (j / 12) + 11) * 23 + ((i % 12) - (j % 12) + 11);
    float bv = tab[rt * 12 + h];
    CM[e] = mask[m * (NTOK * NTOK) + i * NTOK + j] + 16.0f / (1.0f + __expf(-bv));
}

// ---------------- GEMM: C[m,n] = A[m,:]·B[n,:] + bias[n]; A (M,K), B (N,K) fp16 ----------------
// 256x128 tile, 512 threads / 8 waves (each wave 64x64). 1D grid, XCD-swizzled.
template <typename OutT>
__global__ __launch_bounds__(512) void gemm_bt(const _Float16* __restrict__ A,
                                               const _Float16* __restrict__ B,
                                               const float* __restrict__ bias,
                                               OutT* __restrict__ C, int M, int N, int K) {
    __shared__ __align__(16) _Float16 As[256 * 32];   // 16 KB
    __shared__ __align__(16) _Float16 Bs[128 * 32];   //  8 KB
    const int t = threadIdx.x;
    const int wv = t >> 6, l = t & 63;
    const int wm = wv >> 1, wn = wv & 1;              // wm 0..3 (M), wn 0..1 (N)
    const int lr = l & 15, lk = l >> 4;

    const int ntn = N >> 7;                           // N-tiles
    const int t8 = gridDim.x >> 3;                    // tiles per XCD
    const int tile = (blockIdx.x & 7) * t8 + (blockIdx.x >> 3);
    const long m0 = (long)(tile / ntn) * 256, n0 = (long)(tile % ntn) * 128;

    const int srow = t >> 2, scol = (t & 3) * 8;      // srow 0..127
    const _Float16* ag = A + (m0 + srow) * (long)K + scol;
    const _Float16* bg = B + (n0 + srow) * (long)K + scol;
    _Float16* asd = As + t * 8;
    _Float16* bsd = Bs + t * 8;

    floatx4 acc[4][4] = {};

    for (int k0 = 0; k0 < K; k0 += 32) {
        llds16(ag, asd);                              // A rows 0..127
        llds16(ag + 128 * (long)K, asd + 4096);       // A rows 128..255
        llds16(bg, bsd);                              // B rows 0..127
        ag += 32; bg += 32;
        __syncthreads();
        half8 af[4], bf[4];
#pragma unroll
        for (int fi = 0; fi < 4; fi++)
            af[fi] = *(const half8*)&As[(wm * 64 + fi * 16 + lr) * 32 + lk * 8];
#pragma unroll
        for (int fj = 0; fj < 4; fj++)
            bf[fj] = *(const half8*)&Bs[(wn * 64 + fj * 16 + lr) * 32 + lk * 8];
#pragma unroll
        for (int fi = 0; fi < 4; fi++)
#pragma unroll
            for (int fj = 0; fj < 4; fj++)
                acc[fi][fj] = __builtin_amdgcn_mfma_f32_16x16x32_f16(af[fi], bf[fj], acc[fi][fj], 0, 0, 0);
        __syncthreads();
    }

#pragma unroll
    for (int fi = 0; fi < 4; fi++) {
        const long row = m0 + wm * 64 + fi * 16 + lk * 4;
#pragma unroll
        for (int fj = 0; fj < 4; fj++) {
            const long col = n0 + wn * 64 + fj * 16 + lr;
            const float bv = bias[col];
#pragma unroll
            for (int r = 0; r < 4; r++) {
                float v = acc[fi][fj][r] + bv;
                C[(row + r) * (long)N + col] = (OutT)v;
            }
        }
    }
}

// ---------------- windowed attention: one block per (window, head), 9 waves ----------------
__global__ __launch_bounds__(576) void attn_win(const _Float16* __restrict__ qkv,
                                                const float* __restrict__ CM,
                                                const float* __restrict__ lscale,
                                                _Float16* __restrict__ O) {
    __shared__ __align__(16) _Float16 Kn[NTOK * HD];        // 9216 B
    __shared__ __align__(16) _Float16 Vt[HD * NTOK];        // 9216 B (transposed: [d][token])
    __shared__ __align__(16) _Float16 P[9 * 16 * NTOK];     // 41472 B (per-wave 16x144)

    const int bid = blockIdx.x;
    const int w = bid / NH, h = bid % NH;
    const int t = threadIdx.x;
    const int wv = t >> 6, l = t & 63;
    const int lr = l & 15, lk = l >> 4;

    const float sc = expf(fminf(lscale[h], 4.6051701859880914f));  // exp(min(ls, log(100)))

    // ---- stage K (normalized) and V (transposed) ----
    {
        const int row = t >> 2, part = t & 3;
        const size_t base = (size_t)(w * NTOK + row) * QKVN + h * HD + part * 8;
        half8 kv = *(const half8*)(qkv + base + CDIM);
        float ss = 0.f;
#pragma unroll
        for (int j = 0; j < 8; j++) { float f = (float)kv[j]; ss += f * f; }
        ss += __shfl_xor(ss, 1); ss += __shfl_xor(ss, 2);
        float inv = 1.0f / fmaxf(sqrtf(ss), 1e-12f);
        half8 kn;
#pragma unroll
        for (int j = 0; j < 8; j++) kn[j] = (_Float16)((float)kv[j] * inv);
        *(half8*)&Kn[row * HD + part * 8] = kn;

        half8 vv = *(const half8*)(qkv + base + 2 * CDIM);
#pragma unroll
        for (int j = 0; j < 8; j++) Vt[(part * 8 + j) * NTOK + row] = vv[j];
    }
    __syncthreads();

    // ---- Q fragment for this wave's 16 rows: load global, normalize, fold in scale ----
    half8 aq;
    {
        const size_t qb = (size_t)(w * NTOK + wv * 16 + lr) * QKVN + h * HD + lk * 8;
        half8 q = *(const half8*)(qkv + qb);
        float ss = 0.f;
#pragma unroll
        for (int j = 0; j < 8; j++) { float f = (float)q[j]; ss += f * f; }
        ss += __shfl_xor(ss, 16); ss += __shfl_xor(ss, 32);
        float inv = sc / fmaxf(sqrtf(ss), 1e-12f);
#pragma unroll
        for (int j = 0; j < 8; j++) aq[j] = (_Float16)((float)q[j] * inv);
    }

    // ---- S = Qn Kn^T (16 x 144 per wave), + CM, softmax ----
    floatx4 s[9];
#pragma unroll
    for (int cj = 0; cj < 9; cj++) {
        half8 bk = *(const half8*)&Kn[(cj * 16 + lr) * HD + lk * 8];
        floatx4 z = {};
        s[cj] = __builtin_amdgcn_mfma_f32_16x16x32_f16(aq, bk, z, 0, 0, 0);
    }
    const float* cmb = CM + (size_t)((w & 3) * NH + h) * (NTOK * NTOK)
                     + (wv * 16 + lk * 4) * NTOK + lr;
#pragma unroll
    for (int cj = 0; cj < 9; cj++)
#pragma unroll
        for (int r = 0; r < 4; r++) s[cj][r] += cmb[r * NTOK + cj * 16];

    float sm[4];
#pragma unroll
    for (int r = 0; r < 4; r++) {
        float m = s[0][r];
#pragma unroll
        for (int cj = 1; cj < 9; cj++) m = fmaxf(m, s[cj][r]);
        m = fmaxf(m, __shfl_xor(m, 1)); m = fmaxf(m, __shfl_xor(m, 2));
        m = fmaxf(m, __shfl_xor(m, 4)); m = fmaxf(m, __shfl_xor(m, 8));
        float sum = 0.f;
#pragma unroll
        for (int cj = 0; cj < 9; cj++) { s[cj][r] = __expf(s[cj][r] - m); sum += s[cj][r]; }
        sum += __shfl_xor(sum, 1); sum += __shfl_xor(sum, 2);
        sum += __shfl_xor(sum, 4); sum += __shfl_xor(sum, 8);
        sm[r] = sum;
    }

    // ---- P -> LDS (C-layout rows == lk*4+r), then PV via MFMA ----
    // P is per-wave; DS ops are wave-ordered -> no block barrier needed here.
    _Float16* Pw = P + wv * 16 * NTOK;
#pragma unroll
    for (int cj = 0; cj < 9; cj++)
#pragma unroll
        for (int r = 0; r < 4; r++)
            Pw[(lk * 4 + r) * NTOK + cj * 16 + lr] = (_Float16)s[cj][r];

    floatx4 o0 = {}, o1 = {};
#pragma unroll
    for (int kb = 0; kb < 4; kb++) {
        half8 ap = *(const half8*)&Pw[lr * NTOK + kb * 32 + lk * 8];
        half8 b0 = *(const half8*)&Vt[lr * NTOK + kb * 32 + lk * 8];
        half8 b1 = *(const half8*)&Vt[(16 + lr) * NTOK + kb * 32 + lk * 8];
        o0 = __builtin_amdgcn_mfma_f32_16x16x32_f16(ap, b0, o0, 0, 0, 0);
        o1 = __builtin_amdgcn_mfma_f32_16x16x32_f16(ap, b1, o1, 0, 0, 0);
    }
    {   // K tail: tokens 128..143 via legacy 16x16x16 MFMA
        half4v at  = *(const half4v*)&Pw[lr * NTOK + 128 + lk * 4];
        half4v bt0 = *(const half4v*)&Vt[lr * NTOK + 128 + lk * 4];
        half4v bt1 = *(const half4v*)&Vt[(16 + lr) * NTOK + 128 + lk * 4];
        o0 = __builtin_amdgcn_mfma_f32_16x16x16f16(at, bt0, o0, 0, 0, 0);
        o1 = __builtin_amdgcn_mfma_f32_16x16x16f16(at, bt1, o1, 0, 0, 0);
    }

    const size_t ob = (size_t)(w * NTOK + wv * 16 + lk * 4) * CDIM + h * HD;
#pragma unroll
    for (int r = 0; r < 4; r++) {
        float inv = 1.0f / sm[r];
        O[ob + r * CDIM + lr]      = (_Float16)(o0[r] * inv);
        O[ob + r * CDIM + 16 + lr] = (_Float16)(o1[r] * inv);
    }
}

extern "C" void kernel_launch(void* const* d_in, const int* in_sizes, int n_in,
                              void* d_out, int out_size, void* d_ws, size_t ws_size,
                              hipStream_t stream) {
    const float* x     = (const float*)d_in[0];
    const float* mask  = (const float*)d_in[1];
    const float* qkv_w = (const float*)d_in[2];
    const float* qkv_b = (const float*)d_in[3];
    const float* lsc   = (const float*)d_in[4];
    const float* cw1   = (const float*)d_in[5];
    const float* cb1   = (const float*)d_in[6];
    const float* cw2   = (const float*)d_in[7];
    const float* pw    = (const float*)d_in[8];
    const float* pb    = (const float*)d_in[9];
    (void)in_sizes; (void)n_in; (void)out_size; (void)ws_size;

    char* ws = (char*)d_ws;
    float*    tab  = (float*)(ws);                    //    25,392 B
    float*    CM   = (float*)(ws + 25600);            // 3,981,312 B
    _Float16* qw_h = (_Float16*)(ws + 4006912);       //   884,736 B
    _Float16* pw_h = (_Float16*)(ws + 4891648);       //   294,912 B
    _Float16* x_h  = (_Float16*)(ws + 5186560);       // 56,623,104 B (reused as o_h after QKV GEMM)
    _Float16* qkvh = (_Float16*)(ws + 61809664);      // 169,869,312 B ; total ~221 MB
    _Float16* o_h  = x_h;

    cast_f2h<<<(MROWS * CDIM / 8) / 256, 256, 0, stream>>>(x, x_h, MROWS * CDIM / 8);
    cast_weights<<<(QKVN * CDIM / 8 + CDIM * CDIM / 8 + 255) / 256, 256, 0, stream>>>(
        qkv_w, qw_h, pw, pw_h);
    cpb_table<<<1, 576, 0, stream>>>(cw1, cb1, cw2, tab);
    build_cm<<<(4 * NH * NTOK * NTOK + 255) / 256, 256, 0, stream>>>(mask, tab, CM);

    gemm_bt<_Float16><<<(QKVN / 128) * (MROWS / 256), 512, 0, stream>>>(
        x_h, qw_h, qkv_b, qkvh, MROWS, QKVN, CDIM);

    attn_win<<<BW * NH, 576, 0, stream>>>(qkvh, CM, lsc, o_h);

    gemm_bt<float><<<(CDIM / 128) * (MROWS / 256), 512, 0, stream>>>(
        o_h, pw_h, pb, (float*)d_out, MROWS, CDIM, CDIM);
}